// Round 1
// baseline (1272.696 us; speedup 1.0000x reference)
//
#include <hip/hip_runtime.h>
#include <hip/hip_bf16.h>
#include <cstdint>

#define NTOK 8192     // B*S
#define DIM  1024
#define NE   31       // routed experts
#define NZ   32       // routed + shared
#define KTOP 3

typedef __attribute__((ext_vector_type(8))) short short8;
typedef __attribute__((ext_vector_type(4))) float f32x4;

__device__ __forceinline__ short f2bf(float f){
  unsigned u = __builtin_bit_cast(unsigned, f);
  u = (u + 0x7fffu + ((u >> 16) & 1u)) >> 16;
  return (short)u;
}

__device__ __forceinline__ void gl2lds16(const void* g, void* l){
  __builtin_amdgcn_global_load_lds(
      (const __attribute__((address_space(1))) void*)(uintptr_t)g,
      (__attribute__((address_space(3))) void*)(uintptr_t)l,
      16, 0, 0);
}

// ---------------- cast x (fp32 -> bf16) ----------------
__global__ void cast_x_kernel(const float* __restrict__ x, short* __restrict__ xb){
  size_t i = (size_t)blockIdx.x * 256 + threadIdx.x;   // 1,048,576 threads, 8 elems each
  const float4* p = reinterpret_cast<const float4*>(x) + i * 2;
  float4 a = p[0], b = p[1];
  short8 o;
  o[0]=f2bf(a.x); o[1]=f2bf(a.y); o[2]=f2bf(a.z); o[3]=f2bf(a.w);
  o[4]=f2bf(b.x); o[5]=f2bf(b.y); o[6]=f2bf(b.z); o[7]=f2bf(b.w);
  *reinterpret_cast<short8*>(xb + i * 8) = o;
}

// ---------------- out = x ----------------
__global__ void init_out_kernel(const float* __restrict__ x, float* __restrict__ out){
  size_t i = (size_t)blockIdx.x * 256 + threadIdx.x;   // 2,097,152 float4
  reinterpret_cast<float4*>(out)[i] = reinterpret_cast<const float4*>(x)[i];
}

// ---------------- transpose + cast weights: W[k][n] fp32 -> WT[n][k] bf16 ----------------
__global__ void transpose_cast_kernel(const float* __restrict__ We1, const float* __restrict__ ws1,
                                      const float* __restrict__ We2, const float* __restrict__ ws2,
                                      short* __restrict__ WT1, short* __restrict__ WT2){
  const int z = blockIdx.z;
  const float* src; short* dst;
  if (z < NZ){ src = (z < NE) ? (We1 + ((size_t)z << 20)) : ws1; dst = WT1 + ((size_t)z << 20); }
  else { int e = z - NZ; src = (e < NE) ? (We2 + ((size_t)e << 20)) : ws2; dst = WT2 + ((size_t)e << 20); }
  __shared__ float tile[32][33];
  const int tx = threadIdx.x, ty = threadIdx.y;
  const int c0 = blockIdx.x << 5, r0 = blockIdx.y << 5;
#pragma unroll
  for (int j = 0; j < 4; j++) tile[ty*4+j][tx] = src[(size_t)(r0 + ty*4 + j) * DIM + c0 + tx];
  __syncthreads();
#pragma unroll
  for (int j = 0; j < 4; j++) dst[(size_t)(c0 + ty*4 + j) * DIM + r0 + tx] = f2bf(tile[tx][ty*4+j]);
}

// ---------------- router: softmax + top-3, bucket tokens per expert ----------------
__global__ void router_kernel(const float* __restrict__ x, const float* __restrict__ Wr,
                              const float* __restrict__ br, int* __restrict__ cnt,
                              int* __restrict__ tokmap, float* __restrict__ gates){
  const int tok = blockIdx.x;
  __shared__ float xs[DIM];
  __shared__ float logit[NE];
  const int t = threadIdx.x;
  const float4* xr = reinterpret_cast<const float4*>(x + (size_t)tok * DIM);
  for (int i = t; i < DIM/4; i += 256) reinterpret_cast<float4*>(xs)[i] = xr[i];
  __syncthreads();
  const int w = t >> 6, l = t & 63;
  for (int e = w; e < NE; e += 4){
    float s = 0.f;
    for (int k = l; k < DIM; k += 64) s += xs[k] * Wr[(size_t)k * NE + e];
    for (int off = 32; off; off >>= 1) s += __shfl_down(s, off);
    if (l == 0) logit[e] = s + br[e];
  }
  __syncthreads();
  if (w == 0){
    float v = (l < NE) ? logit[l] : -3.0e38f;
    float mx = v;
    for (int off = 32; off; off >>= 1) mx = fmaxf(mx, __shfl_xor(mx, off));
    float ex = (l < NE) ? expf(v - mx) : 0.f;
    float sm = ex;
    for (int off = 32; off; off >>= 1) sm += __shfl_xor(sm, off);
    float p = ex / sm;                 // softmax over all 31 experts
    for (int it = 0; it < KTOP; it++){
      float bm = p; int bi = l;
      for (int off = 32; off; off >>= 1){
        float om = __shfl_xor(bm, off); int oi = __shfl_xor(bi, off);
        if (om > bm || (om == bm && oi < bi)){ bm = om; bi = oi; }
      }
      if (l == 0){
        int pos = atomicAdd(&cnt[bi], 1);
        tokmap[bi * NTOK + pos] = tok;
        gates[bi * NTOK + pos] = bm;
      }
      if (l == bi) p = -1.f;
    }
  }
}

// ---------------- exclusive prefix over counts ----------------
__global__ void prefix_kernel(const int* __restrict__ cnt, int* __restrict__ ebase){
  if (threadIdx.x == 0){
    int s = 0;
    for (int e = 0; e < NE; e++){ ebase[e] = s; s += cnt[e]; }
    ebase[NE] = s;
  }
}

// ---------------- MFMA GEMM: PHASE 1 = X@W1+b -> gelu -> H(bf16); PHASE 2 = H@W2+b, gated atomic scatter ----------------
template<int PHASE>
__global__ __launch_bounds__(256, 2)
void ffn_gemm(const short* __restrict__ Abase, const short* __restrict__ WT,
              const float* __restrict__ BiasE, const float* __restrict__ BiasS,
              const int* __restrict__ cnt, const int* __restrict__ ebase,
              const int* __restrict__ tokmap, const float* __restrict__ gates,
              short* __restrict__ Hout, float* __restrict__ out)
{
  const int z  = blockIdx.z;
  const int cz = (z == NE) ? NTOK : cnt[z];
  const int m0 = blockIdx.y << 7;
  if (m0 >= cz) return;
  const int n0 = blockIdx.x << 7;
  const float* __restrict__ bias = (z == NE) ? BiasS : (BiasE + z * DIM);

  __shared__ short As[128 * 32];
  __shared__ short Bs[128 * 32];

  const int t = threadIdx.x;
  const int w = t >> 6;
  const int l = t & 63;

  // staging source pointers (2 A-rows, 2 B-rows per thread; 16B per lane per load)
  const short *ap0, *ap1;
  {
    int r0 = m0 + (t >> 2), r1 = r0 + 64;
    if (r0 >= cz) r0 = m0;
    if (r1 >= cz) r1 = m0;
    long row0, row1;
    if (PHASE == 1){
      row0 = (z == NE) ? r0 : tokmap[z * NTOK + r0];
      row1 = (z == NE) ? r1 : tokmap[z * NTOK + r1];
    } else {
      long hb = (z == NE) ? 0 : (NTOK + ebase[z]);
      row0 = hb + r0; row1 = hb + r1;
    }
    ap0 = Abase + row0 * (long)DIM + (t & 3) * 8;
    ap1 = Abase + row1 * (long)DIM + (t & 3) * 8;
  }
  const short* bp0 = WT + ((size_t)z << 20) + (size_t)(n0 + (t >> 2)) * DIM + (t & 3) * 8;
  const short* bp1 = bp0 + (size_t)64 * DIM;

  short* aL0 = &As[w * 512];          // wave-uniform LDS bases (+lane*16B implicit)
  short* aL1 = &As[2048 + w * 512];
  short* bL0 = &Bs[w * 512];
  short* bL1 = &Bs[2048 + w * 512];

  f32x4 acc[4][4] = {};

  const int fr = l & 15;
  const int kc = (l >> 4) * 8;
  const int wr = (w >> 1) * 64;
  const int wc = (w & 1) * 64;

  for (int k0 = 0; k0 < DIM; k0 += 32){
    gl2lds16(ap0 + k0, aL0);
    gl2lds16(ap1 + k0, aL1);
    gl2lds16(bp0 + k0, bL0);
    gl2lds16(bp1 + k0, bL1);
    __syncthreads();                  // drains vmcnt(0): staged data visible
    short8 af[4], bfr[4];
#pragma unroll
    for (int m = 0; m < 4; m++)
      af[m] = *reinterpret_cast<const short8*>(&As[(wr + m * 16 + fr) * 32 + kc]);
#pragma unroll
    for (int n = 0; n < 4; n++)
      bfr[n] = *reinterpret_cast<const short8*>(&Bs[(wc + n * 16 + fr) * 32 + kc]);
#pragma unroll
    for (int m = 0; m < 4; m++)
#pragma unroll
      for (int n = 0; n < 4; n++)
        acc[m][n] = __builtin_amdgcn_mfma_f32_16x16x32_bf16(af[m], bfr[n], acc[m][n], 0, 0, 0);
    __syncthreads();                  // all frag reads done before next stage overwrites
  }

  if (PHASE == 1){
    const long hb = (z == NE) ? 0 : (NTOK + ebase[z]);
#pragma unroll
    for (int m = 0; m < 4; m++){
#pragma unroll
      for (int j = 0; j < 4; j++){
        int r = m0 + wr + m * 16 + ((l >> 4) << 2) + j;
        if (r < cz){
          short* hp = Hout + (hb + r) * (long)DIM + n0 + wc + fr;
#pragma unroll
          for (int n = 0; n < 4; n++){
            float v = acc[m][n][j] + bias[n0 + wc + n * 16 + fr];
            v = 0.5f * v * (1.f + erff(v * 0.7071067811865475f));  // exact-erf GELU
            hp[n * 16] = f2bf(v);
          }
        }
      }
    }
  } else {
#pragma unroll
    for (int m = 0; m < 4; m++){
#pragma unroll
      for (int j = 0; j < 4; j++){
        int r = m0 + wr + m * 16 + ((l >> 4) << 2) + j;
        if (r < cz){
          int tok; float g;
          if (z == NE){ tok = r; g = 1.0f; }
          else { tok = tokmap[z * NTOK + r]; g = gates[z * NTOK + r]; }
          float* op = out + (size_t)tok * DIM + n0 + wc + fr;
#pragma unroll
          for (int n = 0; n < 4; n++){
            float v = acc[m][n][j] + bias[n0 + wc + n * 16 + fr];
            atomicAdd(op + n * 16, g * v);
          }
        }
      }
    }
  }
}

extern "C" void kernel_launch(void* const* d_in, const int* in_sizes, int n_in,
                              void* d_out, int out_size, void* d_ws, size_t ws_size,
                              hipStream_t stream){
  (void)in_sizes; (void)n_in; (void)out_size; (void)ws_size;
  const float* x   = (const float*)d_in[0];
  const float* ws1 = (const float*)d_in[1];
  const float* bs1 = (const float*)d_in[2];
  const float* ws2 = (const float*)d_in[3];
  const float* bs2 = (const float*)d_in[4];
  const float* We1 = (const float*)d_in[5];
  const float* Be1 = (const float*)d_in[6];
  const float* We2 = (const float*)d_in[7];
  const float* Be2 = (const float*)d_in[8];
  const float* Wr  = (const float*)d_in[9];
  const float* br  = (const float*)d_in[10];
  float* out = (float*)d_out;

  // workspace layout (~210 MiB)
  char* ws = (char*)d_ws;
  short* WT1    = (short*)(ws);                          //  64 MiB: [32][1024][1024] bf16 (B^T)
  short* WT2    = (short*)(ws + ((size_t)64  << 20));    //  64 MiB
  short* xb     = (short*)(ws + ((size_t)128 << 20));    //  16 MiB: [8192][1024] bf16
  short* H      = (short*)(ws + ((size_t)144 << 20));    //  64 MiB: [32768][1024] bf16 (8192 shared + 24576 routed)
  int*   tokmap = (int*)  (ws + ((size_t)208 << 20));    //  ~1 MiB: [31][8192]
  float* gates  = (float*)(ws + ((size_t)209 << 20));    //  ~1 MiB
  int*   cnt    = (int*)  (ws + ((size_t)210 << 20));    //  31 ints
  int*   ebase  = (int*)  (ws + ((size_t)210 << 20) + 256); // 32 ints

  hipMemsetAsync(cnt, 0, 32 * sizeof(int), stream);

  cast_x_kernel<<<4096, 256, 0, stream>>>(x, xb);

  {
    dim3 g(32, 32, 64), b(32, 8);
    transpose_cast_kernel<<<g, b, 0, stream>>>(We1, ws1, We2, ws2, WT1, WT2);
  }

  router_kernel<<<NTOK, 256, 0, stream>>>(x, Wr, br, cnt, tokmap, gates);
  prefix_kernel<<<1, 64, 0, stream>>>(cnt, ebase);
  init_out_kernel<<<8192, 256, 0, stream>>>(x, out);

  {
    dim3 g(8, 64, NZ);  // 8 N-tiles, worst-case 64 M-tiles (early-exit), 31 routed + 1 shared
    ffn_gemm<1><<<g, 256, 0, stream>>>(xb, WT1, Be1, bs1, cnt, ebase, tokmap, gates, H, nullptr);
    ffn_gemm<2><<<g, 256, 0, stream>>>(H,  WT2, Be2, bs2, cnt, ebase, tokmap, gates, nullptr, out);
  }
}